// Round 1
// baseline (368.942 us; speedup 1.0000x reference)
//
#include <hip/hip_runtime.h>
#include <hip/hip_bf16.h>

#define N_NODES 50000
#define N_EDGES 800000
#define HEADS 4
#define OUT_CH 32
#define FDIM (HEADS * OUT_CH)   // 128

// Precompute per-node dot products: a[n,h] = dot(x[n,h,:], w[:32]),
//                                   b[n,h] = dot(x[n,h,:], w[32:])
// Layout in ws: ab[n*8 + h*2 + 0] = a, ab[n*8 + h*2 + 1] = b
__global__ void node_dots_kernel(const float* __restrict__ x,
                                 const float* __restrict__ w,
                                 float* __restrict__ ab,
                                 int n_nodes) {
    int gid = blockIdx.x * blockDim.x + threadIdx.x;
    int node = gid >> 7;          // 128 threads per node
    int t = threadIdx.x & 127;    // channel within node row
    if (node >= n_nodes) return;
    int h = t >> 5;               // head
    int c = t & 31;               // channel within head

    float xv = x[node * FDIM + t];
    float pa = xv * w[c];
    float pb = xv * w[OUT_CH + c];

    // reduce over the 32 lanes of this head (XOR masks stay within 32-lane half-wave)
    #pragma unroll
    for (int m = 16; m >= 1; m >>= 1) {
        pa += __shfl_xor(pa, m);
        pb += __shfl_xor(pb, m);
    }
    if (c == 0) {
        ab[node * 8 + h * 2 + 0] = pa;
        ab[node * 8 + h * 2 + 1] = pb;
    }
}

// One edge per 128 consecutive threads: gather x[j], gate, atomic scatter into out[i]
__global__ void edge_scatter_kernel(const float* __restrict__ x,
                                    const int* __restrict__ ei_arr,
                                    const int* __restrict__ ej_arr,
                                    const float* __restrict__ weights,
                                    const float* __restrict__ ab,
                                    float* __restrict__ out,
                                    int n_edges) {
    int gid = blockIdx.x * blockDim.x + threadIdx.x;
    int e = gid >> 7;             // 128 threads per edge
    int t = threadIdx.x & 127;
    if (e >= n_edges) return;
    int h = t >> 5;

    int i = ei_arr[e];
    int j = ej_arr[e];

    float alpha = ab[i * 8 + h * 2 + 0] + ab[j * 8 + h * 2 + 1];
    float sig = 1.0f / (1.0f + __expf(-alpha));
    float beta = weights[e] * sig;

    float msg = x[j * FDIM + t] * beta;
    atomicAdd(&out[i * FDIM + t], msg);
}

extern "C" void kernel_launch(void* const* d_in, const int* in_sizes, int n_in,
                              void* d_out, int out_size, void* d_ws, size_t ws_size,
                              hipStream_t stream) {
    const float* x       = (const float*)d_in[0];   // (N_NODES, 128) f32
    const int*   eidx    = (const int*)d_in[1];     // (2, N_EDGES)
    const float* weights = (const float*)d_in[2];   // (N_EDGES,) f32
    const float* w       = (const float*)d_in[3];   // (64,) f32
    float* out = (float*)d_out;                     // (N_NODES, 128) f32
    float* ab  = (float*)d_ws;                      // N_NODES*8 floats = 1.6 MB

    const int* ei_arr = eidx;
    const int* ej_arr = eidx + N_EDGES;

    // zero accumulator output (atomics accumulate into it)
    hipMemsetAsync(d_out, 0, (size_t)out_size * sizeof(float), stream);

    // 1) per-node dot products
    {
        int threads_total = N_NODES * FDIM;
        int block = 256;
        int grid = (threads_total + block - 1) / block;
        node_dots_kernel<<<grid, block, 0, stream>>>(x, w, ab, N_NODES);
    }

    // 2) per-edge gather + gate + atomic scatter
    {
        long long threads_total = (long long)N_EDGES * FDIM;
        int block = 256;
        long long grid = (threads_total + block - 1) / block;
        edge_scatter_kernel<<<(int)grid, block, 0, stream>>>(
            x, ei_arr, ej_arr, weights, ab, out, N_EDGES);
    }
}